// Round 4
// baseline (895.299 us; speedup 1.0000x reference)
//
#include <hip/hip_runtime.h>

typedef float f32x4 __attribute__((ext_vector_type(4)));
typedef short short8v __attribute__((ext_vector_type(8)));

__device__ __forceinline__ float bf2f(unsigned short h) {
  union { unsigned int u; float f; } v; v.u = ((unsigned int)h) << 16; return v.f;
}
__device__ __forceinline__ unsigned short f2bf(float f) {
  union { float f; unsigned int u; } v; v.f = f;
  unsigned int u = v.u;
  return (unsigned short)((u + 0x7fffu + ((u >> 16) & 1u)) >> 16);
}
// load 8 consecutive f32, round to bf16 MFMA fragment
__device__ __forceinline__ short8v ld8f(const float* __restrict__ p) {
  f32x4 a = *(const f32x4*)p;
  f32x4 b = *(const f32x4*)(p + 4);
  short8v r;
  r[0] = (short)f2bf(a[0]); r[1] = (short)f2bf(a[1]);
  r[2] = (short)f2bf(a[2]); r[3] = (short)f2bf(a[3]);
  r[4] = (short)f2bf(b[0]); r[5] = (short)f2bf(b[1]);
  r[6] = (short)f2bf(b[2]); r[7] = (short)f2bf(b[3]);
  return r;
}

// btab[h][225] = 16*sigmoid( relu(table@w1^T + b1) @ w2^T )   (all f32)
__global__ void cpb_kernel(const float* __restrict__ w1, const float* __restrict__ b1,
                           const float* __restrict__ w2, float* __restrict__ btab) {
  __shared__ float h1s[512];
  int t = threadIdx.x;
  int i = blockIdx.x;            // 0..224
  int a = i / 15, b = i % 15;
  float va = (float)(a - 7) * (8.0f / 7.0f);
  float vb = (float)(b - 7) * (8.0f / 7.0f);
  float tx = copysignf(log2f(fabsf(va) + 1.0f) * (1.0f / 3.0f), va);
  float ty = copysignf(log2f(fabsf(vb) + 1.0f) * (1.0f / 3.0f), vb);
  float h = tx * w1[2 * t] + ty * w1[2 * t + 1] + b1[t];
  h1s[t] = fmaxf(h, 0.0f);
  __syncthreads();
  int head = t >> 6, lane = t & 63;
  float s = 0.f;
  for (int j = lane; j < 512; j += 64) s += h1s[j] * w2[head * 512 + j];
  #pragma unroll
  for (int m = 1; m < 64; m <<= 1) s += __shfl_xor(s, m, 64);
  if (lane == 0) btab[head * 225 + i] = 16.0f / (1.0f + __expf(-s));
}

// LDS per wave slice (15616 B at wave*15616):
//   Q[64][40] bf16 @0, K[64][40] @5120B, Vt[32][80] @10240B, rk f32[64] @15360B
//   P[64][80] overlays Q+K; O[2][64][40] overlays P. After barrier: Zs[64][264] bf16 @0.
__global__ __launch_bounds__(256, 2)
void swin_kernel(const float* __restrict__ img,
                 const float* __restrict__ wq, const float* __restrict__ bq,
                 const float* __restrict__ wk, const float* __restrict__ bk,
                 const float* __restrict__ wv, const float* __restrict__ bv,
                 const float* __restrict__ wo, const float* __restrict__ bo,
                 const float* __restrict__ ls,
                 const float* __restrict__ btab_g,
                 float* __restrict__ out) {
  __shared__ __align__(16) unsigned char smem[62464];
  const int tid = threadIdx.x;
  const int wave = tid >> 6, lane = tid & 63;
  const int quad = lane >> 4, l16 = lane & 15;
  const int bid = blockIdx.x;
  const int bimg = bid >> 2, w = bid & 3;
  const int wr = (w >> 1) * 8, wc = (w & 1) * 8;
  const bool wrh = (w & 2) != 0, wch = (w & 1) != 0;

  unsigned short* slice = (unsigned short*)(smem + wave * 15616);
  unsigned short* Qs = slice;                 // [64][40]
  unsigned short* Ks = slice + 2560;          // [64][40]
  unsigned short* Vt = slice + 5120;          // [32][80]
  float* rk = (float*)(smem + wave * 15616 + 15360);  // [64]
  unsigned short* Ps = slice;                 // [64][80] overlay

  int pixbase[4];
  #pragma unroll
  for (int mt = 0; mt < 4; ++mt) {
    int t = mt * 16 + l16;
    int pi = (wr + (t >> 3) + 12) & 15;
    int pj = (wc + (t & 7) + 12) & 15;
    pixbase[mt] = (bimg * 256 + pi * 16 + pj) * 256;
  }

  f32x4 oacc[2][4][2];
  const f32x4 zf4 = {0.f, 0.f, 0.f, 0.f};

  #pragma unroll
  for (int hh = 0; hh < 2; ++hh) {
    const int h = wave * 2 + hh;
    float rq[4][4];

    // x fragments: A[m=l16][k=quad*8+j]  (f32 -> bf16; 2nd pass L1-hits)
    short8v xf[8][4];
    #pragma unroll
    for (int kt = 0; kt < 8; ++kt)
      #pragma unroll
      for (int mt = 0; mt < 4; ++mt)
        xf[kt][mt] = ld8f(img + pixbase[mt] + kt * 32 + quad * 8);

    // ---- QKV projections, head h (out channels h*32..h*32+31) ----
    #pragma unroll
    for (int mat = 0; mat < 3; ++mat) {
      const float* W  = (mat == 0) ? wq : ((mat == 1) ? wk : wv);
      const float* bb = (mat == 0) ? bq : ((mat == 1) ? bk : bv);
      f32x4 acc[4][2];
      #pragma unroll
      for (int mt = 0; mt < 4; ++mt) { acc[mt][0] = zf4; acc[mt][1] = zf4; }
      #pragma unroll
      for (int kt = 0; kt < 8; ++kt) {
        #pragma unroll
        for (int nt = 0; nt < 2; ++nt) {
          int row = h * 32 + nt * 16 + l16;
          short8v bfv = ld8f(W + row * 256 + kt * 32 + quad * 8);
          #pragma unroll
          for (int mt = 0; mt < 4; ++mt)
            acc[mt][nt] = __builtin_amdgcn_mfma_f32_16x16x32_bf16(xf[kt][mt], bfv, acc[mt][nt], 0, 0, 0);
        }
      }
      float bv0 = bb[h * 32 + l16];
      float bv1 = bb[h * 32 + 16 + l16];
      if (mat < 2) {
        unsigned short* dst = (mat == 0) ? Qs : Ks;
        #pragma unroll
        for (int mt = 0; mt < 4; ++mt) {
          #pragma unroll
          for (int r = 0; r < 4; ++r) {
            float q0 = acc[mt][0][r] + bv0;
            float q1 = acc[mt][1][r] + bv1;
            float ss = q0 * q0 + q1 * q1;
            ss += __shfl_xor(ss, 1); ss += __shfl_xor(ss, 2);
            ss += __shfl_xor(ss, 4); ss += __shfl_xor(ss, 8);
            float rinv = rsqrtf(fmaxf(ss, 1e-24f));
            int row = mt * 16 + quad * 4 + r;
            dst[row * 40 + l16]      = f2bf(q0);   // raw; normalized in f32 at softmax
            dst[row * 40 + 16 + l16] = f2bf(q1);
            if (mat == 0) rq[mt][r] = rinv;
            else if (l16 == 0) rk[row] = rinv;
          }
        }
      } else {
        #pragma unroll
        for (int mt = 0; mt < 4; ++mt)
          #pragma unroll
          for (int r = 0; r < 4; ++r) {
            int tok = mt * 16 + quad * 4 + r;
            Vt[l16 * 80 + tok]        = f2bf(acc[mt][0][r] + bv0);
            Vt[(16 + l16) * 80 + tok] = f2bf(acc[mt][1][r] + bv1);
          }
      }
    }

    // ---- S = Q.K^T (raw bf16, f32 accum) ----
    short8v qa[4], kb[4];
    #pragma unroll
    for (int mt = 0; mt < 4; ++mt)
      qa[mt] = *(const short8v*)(Qs + (mt * 16 + l16) * 40 + quad * 8);
    #pragma unroll
    for (int nt = 0; nt < 4; ++nt)
      kb[nt] = *(const short8v*)(Ks + (nt * 16 + l16) * 40 + quad * 8);
    f32x4 s[4][4];
    #pragma unroll
    for (int mt = 0; mt < 4; ++mt)
      #pragma unroll
      for (int nt = 0; nt < 4; ++nt)
        s[mt][nt] = __builtin_amdgcn_mfma_f32_16x16x32_bf16(qa[mt], kb[nt], zf4, 0, 0, 0);

    // ---- normalize + scale + bias + mask + softmax -> P ----
    float scale = __expf(fminf(ls[h], 4.60517019f));
    const float* bg = btab_g + h * 225;
    float rkv[4];
    int kio[4], kjo[4], kgr[4], kgc[4];
    #pragma unroll
    for (int nt = 0; nt < 4; ++nt) {
      int c = nt * 16 + l16;
      rkv[nt] = rk[c];
      kio[nt] = c >> 3; kjo[nt] = c & 7;
      kgr[nt] = wrh ? (kio[nt] < 4 ? 1 : 2) : 0;
      kgc[nt] = wch ? (kjo[nt] < 4 ? 1 : 2) : 0;
    }
    #pragma unroll
    for (int mt = 0; mt < 4; ++mt) {
      #pragma unroll
      for (int r = 0; r < 4; ++r) {
        int qrow = mt * 16 + quad * 4 + r;
        int qi = qrow >> 3, qj = qrow & 7;
        int qgr = wrh ? (qi < 4 ? 1 : 2) : 0;
        int qgc = wch ? (qj < 4 ? 1 : 2) : 0;
        float qs = rq[mt][r] * scale;
        float rv[4]; float mx = -30000.0f;
        #pragma unroll
        for (int nt = 0; nt < 4; ++nt) {
          int idx = (qi - kio[nt] + 7) * 15 + (qj - kjo[nt] + 7);
          float val = s[mt][nt][r] * qs * rkv[nt] + bg[idx];
          if ((qgr != kgr[nt]) || (qgc != kgc[nt])) val = -30000.0f;
          rv[nt] = val; mx = fmaxf(mx, val);
        }
        mx = fmaxf(mx, __shfl_xor(mx, 1)); mx = fmaxf(mx, __shfl_xor(mx, 2));
        mx = fmaxf(mx, __shfl_xor(mx, 4)); mx = fmaxf(mx, __shfl_xor(mx, 8));
        float sum = 0.f;
        #pragma unroll
        for (int nt = 0; nt < 4; ++nt) {
          rv[nt] = __expf(rv[nt] - mx);
          sum += rv[nt];
        }
        sum += __shfl_xor(sum, 1); sum += __shfl_xor(sum, 2);
        sum += __shfl_xor(sum, 4); sum += __shfl_xor(sum, 8);
        float rs = 1.0f / sum;
        #pragma unroll
        for (int nt = 0; nt < 4; ++nt)
          Ps[qrow * 80 + nt * 16 + l16] = f2bf(rv[nt] * rs);
      }
    }

    // ---- O_h = P.V ----
    #pragma unroll
    for (int kt2 = 0; kt2 < 2; ++kt2) {
      short8v pa[4], vb2[2];
      #pragma unroll
      for (int mt = 0; mt < 4; ++mt)
        pa[mt] = *(const short8v*)(Ps + (mt * 16 + l16) * 80 + kt2 * 32 + quad * 8);
      #pragma unroll
      for (int nt2 = 0; nt2 < 2; ++nt2)
        vb2[nt2] = *(const short8v*)(Vt + (nt2 * 16 + l16) * 80 + kt2 * 32 + quad * 8);
      #pragma unroll
      for (int mt = 0; mt < 4; ++mt)
        #pragma unroll
        for (int nt2 = 0; nt2 < 2; ++nt2) {
          f32x4 c = (kt2 == 0) ? zf4 : oacc[hh][mt][nt2];
          oacc[hh][mt][nt2] = __builtin_amdgcn_mfma_f32_16x16x32_bf16(pa[mt], vb2[nt2], c, 0, 0, 0);
        }
    }
  }

  // ---- O (both heads) -> wave slice ----
  #pragma unroll
  for (int hh = 0; hh < 2; ++hh) {
    unsigned short* Od = slice + hh * 2560;
    #pragma unroll
    for (int mt = 0; mt < 4; ++mt)
      #pragma unroll
      for (int nt2 = 0; nt2 < 2; ++nt2)
        #pragma unroll
        for (int r = 0; r < 4; ++r)
          Od[(mt * 16 + quad * 4 + r) * 40 + nt2 * 16 + l16] = f2bf(oacc[hh][mt][nt2][r]);
  }
  __syncthreads();

  // ---- Z = O @ wo^T, wave owns out-channels [wave*64, wave*64+64) ----
  f32x4 z[4][4];
  #pragma unroll
  for (int mt = 0; mt < 4; ++mt)
    #pragma unroll
    for (int nt = 0; nt < 4; ++nt) z[mt][nt] = zf4;
  #pragma unroll
  for (int kt = 0; kt < 8; ++kt) {   // kt = head (32 k-channels)
    const unsigned short* Ob = (const unsigned short*)(smem + (kt >> 1) * 15616) + (kt & 1) * 2560;
    short8v oa[4];
    #pragma unroll
    for (int mt = 0; mt < 4; ++mt)
      oa[mt] = *(const short8v*)(Ob + (mt * 16 + l16) * 40 + quad * 8);
    #pragma unroll
    for (int nt = 0; nt < 4; ++nt) {
      int row = wave * 64 + nt * 16 + l16;
      short8v wb = ld8f(wo + row * 256 + kt * 32 + quad * 8);
      #pragma unroll
      for (int mt = 0; mt < 4; ++mt)
        z[mt][nt] = __builtin_amdgcn_mfma_f32_16x16x32_bf16(oa[mt], wb, z[mt][nt], 0, 0, 0);
    }
  }
  __syncthreads();

  // ---- Z -> LDS staging [64][264] bf16, + bo ----
  unsigned short* Zs = (unsigned short*)smem;
  #pragma unroll
  for (int nt = 0; nt < 4; ++nt) {
    int col = wave * 64 + nt * 16 + l16;
    float bov = bo[col];
    #pragma unroll
    for (int mt = 0; mt < 4; ++mt)
      #pragma unroll
      for (int r = 0; r < 4; ++r)
        Zs[(mt * 16 + quad * 4 + r) * 264 + col] = f2bf(z[mt][nt][r] + bov);
  }
  __syncthreads();

  // ---- coalesced f32 store, inverse roll ----
  #pragma unroll
  for (int p8 = 0; p8 < 8; ++p8) {
    int p = p8 * 8 + (tid >> 5);
    int ch = (tid & 31) * 8;
    const unsigned short* zp = Zs + p * 264 + ch;
    short8v vv = *(const short8v*)zp;
    f32x4 o0, o1;
    o0[0] = bf2f((unsigned short)vv[0]); o0[1] = bf2f((unsigned short)vv[1]);
    o0[2] = bf2f((unsigned short)vv[2]); o0[3] = bf2f((unsigned short)vv[3]);
    o1[0] = bf2f((unsigned short)vv[4]); o1[1] = bf2f((unsigned short)vv[5]);
    o1[2] = bf2f((unsigned short)vv[6]); o1[3] = bf2f((unsigned short)vv[7]);
    int pi = (wr + (p >> 3) + 12) & 15;
    int pj = (wc + (p & 7) + 12) & 15;
    float* op = out + (bimg * 256 + pi * 16 + pj) * 256 + ch;
    *(f32x4*)op = o0;
    *(f32x4*)(op + 4) = o1;
  }
}

extern "C" void kernel_launch(void* const* d_in, const int* in_sizes, int n_in,
                              void* d_out, int out_size, void* d_ws, size_t ws_size,
                              hipStream_t stream) {
  (void)in_sizes; (void)n_in; (void)out_size; (void)ws_size;
  const float* img = (const float*)d_in[0];
  const float* wq  = (const float*)d_in[1];
  const float* bq  = (const float*)d_in[2];
  const float* wk  = (const float*)d_in[3];
  const float* bk  = (const float*)d_in[4];
  const float* wv  = (const float*)d_in[5];
  const float* bv  = (const float*)d_in[6];
  const float* wo  = (const float*)d_in[7];
  const float* bo  = (const float*)d_in[8];
  const float* ls  = (const float*)d_in[9];
  const float* w1  = (const float*)d_in[10];
  const float* b1  = (const float*)d_in[11];
  const float* w2  = (const float*)d_in[12];
  float* out = (float*)d_out;
  float* btab = (float*)d_ws;   // 1800 floats

  cpb_kernel<<<225, 512, 0, stream>>>(w1, b1, w2, btab);
  swin_kernel<<<2048, 256, 0, stream>>>(img, wq, bq, wk, bk, wv, bv, wo, bo, ls, btab, out);
}